// Round 2
// baseline (407.116 us; speedup 1.0000x reference)
//
#include <hip/hip_runtime.h>

#define N_PROT 8192
#define E_PP   163840
#define E_LP   81920

typedef float        f32x4 __attribute__((ext_vector_type(4)));
typedef unsigned int u32x4 __attribute__((ext_vector_type(4)));
typedef short        s16x8 __attribute__((ext_vector_type(8)));
typedef unsigned short ushort_t;

union frag_cast { u32x4 u; s16x8 s; };

__device__ inline unsigned short f2bf(float f) {
  unsigned int u = __float_as_uint(f);
  u = u + 0x7FFFu + ((u >> 16) & 1u);   // RTNE
  return (unsigned short)(u >> 16);
}

__device__ inline float gelu_tanh(float x) {
  const float c0 = 0.7978845608028654f;
  float inner = c0 * (x + 0.044715f * x * x * x);
  return 0.5f * x * (1.0f + tanhf(inner));
}

// ---------------------------------------------------------------------------
// Pre-transpose weights [K][128]+[K][128] -> k-inner bf16 [K/8][256][8]
// ---------------------------------------------------------------------------
__global__ void build_bt(const float* __restrict__ Watt, const float* __restrict__ Wval,
                         ushort_t* __restrict__ Bt, int K)
{
  int i = blockIdx.x * 256 + threadIdx.x;
  if (i >= K * 256) return;
  int k = i >> 8, n = i & 255;
  float v = (n < 128) ? Watt[(size_t)k * 128 + n] : Wval[(size_t)k * 128 + (n - 128)];
  Bt[(size_t)(k >> 3) * 2048 + n * 8 + (k & 7)] = f2bf(v);
}

// ---------------------------------------------------------------------------
// Edge GATv2: gathered GEMM [E x K] @ [K x 256] + logits + exp + atomic accum
// MODE 0: pp (z = [src_exp(448) | prot[sink](128)]), K=576
// MODE 1: lp (z = [lig[src](128) | prot[sink](128) | eattr(128)]), K=384
// ---------------------------------------------------------------------------
template<int MODE>
__global__ __launch_bounds__(256)
void edge_gat(const float* __restrict__ Afeat,
              const float* __restrict__ prot,
              const float* __restrict__ eattr,
              const int*   __restrict__ eidx,
              const ushort_t* __restrict__ Bt,
              const float* __restrict__ batt,
              const float* __restrict__ avec,
              const float* __restrict__ bval,
              float* __restrict__ num,
              float* __restrict__ den)
{
  constexpr int K = (MODE == 0) ? 576 : 384;
  constexpr int E = (MODE == 0) ? E_PP : E_LP;

  __shared__ alignas(16) ushort_t Asm[64 * 32];      // 4 KB, k-slot XOR swizzled
  __shared__ alignas(16) ushort_t Bsm[4 * 256 * 8];  // 16 KB, [kb][n][8]
  __shared__ float    esm[64 * 4];
  __shared__ int      ssink[64];

  const int t    = threadIdx.x;
  const int lane = t & 63;
  const int w    = t >> 6;
  const int m0   = blockIdx.x * 64;

  const int lr  = t >> 2;       // row this thread stages
  const int lc  = t & 3;        // 8-float chunk within the 32-wide k-step
  const int eid = m0 + lr;
  const int snk = eidx[E + eid];
  int src = 0;
  if (MODE == 1) src = eidx[eid];
  if (lc == 0) ssink[lr] = snk;

  f32x4 acc[4][4];
  #pragma unroll
  for (int i = 0; i < 4; ++i)
    #pragma unroll
    for (int j = 0; j < 4; ++j)
      acc[i][j] = (f32x4){0.f, 0.f, 0.f, 0.f};

  ushort_t* a_dst = (ushort_t*)((char*)Asm + lr * 64 + ((lc ^ ((lr >> 1) & 3)) * 16));

  const int l15 = lane & 15;
  const int kb  = lane >> 4;

  #pragma unroll
  for (int k0 = 0; k0 < K; k0 += 32) {
    // ---- gathered A chunk: 8 floats of row `lr` ----
    const float* ap;
    if (MODE == 0) {
      ap = (k0 < 448) ? (Afeat + (size_t)eid * 448 + (k0 + lc * 8))
                      : (prot  + (size_t)snk * 128 + (k0 - 448 + lc * 8));
    } else {
      const int reg = k0 >> 7;
      const int kk  = (k0 & 127) + lc * 8;
      ap = (reg == 0) ? (Afeat + (size_t)src * 128 + kk)
         : (reg == 1) ? (prot  + (size_t)snk * 128 + kk)
                      : (eattr + (size_t)eid * 128 + kk);
    }
    f32x4 f0 = *(const f32x4*)ap;
    f32x4 f1 = *(const f32x4*)(ap + 4);

    // ---- B chunk (already bf16 k-inner): 4 x 16B per thread ----
    const u32x4* bp = (const u32x4*)Bt + (size_t)k0 * 32;
    u32x4 b0 = bp[t];
    u32x4 b1 = bp[t + 256];
    u32x4 b2 = bp[t + 512];
    u32x4 b3 = bp[t + 768];

    __syncthreads();   // previous step's LDS reads done

    union { unsigned short u[8]; u32x4 v; } pk;
    pk.u[0] = f2bf(f0.x); pk.u[1] = f2bf(f0.y); pk.u[2] = f2bf(f0.z); pk.u[3] = f2bf(f0.w);
    pk.u[4] = f2bf(f1.x); pk.u[5] = f2bf(f1.y); pk.u[6] = f2bf(f1.z); pk.u[7] = f2bf(f1.w);
    *(u32x4*)a_dst = pk.v;

    u32x4* bs = (u32x4*)Bsm;
    bs[t] = b0; bs[t + 256] = b1; bs[t + 512] = b2; bs[t + 768] = b3;

    __syncthreads();   // tiles ready

    frag_cast af[4], bfr[4];
    #pragma unroll
    for (int mb = 0; mb < 4; ++mb) {
      const int row = mb * 16 + l15;
      af[mb].u = *(const u32x4*)((const char*)Asm + row * 64 + ((kb ^ ((row >> 1) & 3)) * 16));
    }
    #pragma unroll
    for (int nb = 0; nb < 4; ++nb) {
      const int n = w * 64 + nb * 16 + l15;
      bfr[nb].u = *(const u32x4*)((const char*)Bsm + kb * 4096 + n * 16);
    }
    #pragma unroll
    for (int mb = 0; mb < 4; ++mb)
      #pragma unroll
      for (int nb = 0; nb < 4; ++nb)
        acc[mb][nb] = __builtin_amdgcn_mfma_f32_16x16x32_bf16(
            af[mb].s, bfr[nb].s, acc[mb][nb], 0, 0, 0);
  }

  // ---- attention logits (waves 0,1 own cols 0..127 = Watt output) ----
  if (w < 2) {
    #pragma unroll
    for (int hl = 0; hl < 2; ++hl) {
      const int   head = w * 2 + hl;
      const float a_lo = avec[head * 32 + l15];
      const float a_hi = avec[head * 32 + 16 + l15];
      const float b_lo = batt[head * 32 + l15];
      const float b_hi = batt[head * 32 + 16 + l15];
      #pragma unroll
      for (int mb = 0; mb < 4; ++mb) {
        #pragma unroll
        for (int j = 0; j < 4; ++j) {
          float hlo = acc[mb][2 * hl][j]     + b_lo;
          float hhi = acc[mb][2 * hl + 1][j] + b_hi;
          hlo = (hlo > 0.f) ? hlo : 0.2f * hlo;
          hhi = (hhi > 0.f) ? hhi : 0.2f * hhi;
          float p = hlo * a_lo + hhi * a_hi;
          p += __shfl_xor(p, 1, 64);
          p += __shfl_xor(p, 2, 64);
          p += __shfl_xor(p, 4, 64);
          p += __shfl_xor(p, 8, 64);
          if (l15 == 0) {
            const float ev  = __expf(p);   // no max-sub: logits bounded (~|4|)
            const int   row = mb * 16 + kb * 4 + j;
            esm[row * 4 + head] = ev;
            atomicAdd(&den[(size_t)ssink[row] * 4 + head], ev);
          }
        }
      }
    }
  }
  __syncthreads();
  // ---- value accumulation (waves 2,3 own cols 128..255 = Wval output) ----
  if (w >= 2) {
    #pragma unroll
    for (int nb = 0; nb < 4; ++nb) {
      const int   col = (w - 2) * 64 + nb * 16 + l15;
      const float bv  = bval[col];
      const int   hd  = col >> 5;
      #pragma unroll
      for (int mb = 0; mb < 4; ++mb) {
        #pragma unroll
        for (int j = 0; j < 4; ++j) {
          const int   row = mb * 16 + kb * 4 + j;
          const float v   = acc[mb][nb][j] + bv;
          atomicAdd(&num[(size_t)ssink[row] * 128 + col], v * esm[row * 4 + hd]);
        }
      }
    }
  }
}

// ---------------------------------------------------------------------------
// LN over 16 rows of 128 (4 waves; wave handles 4 rows, 16 lanes x 8 cols)
// ---------------------------------------------------------------------------
__device__ inline void ln_rows16(const float* __restrict__ src, float* __restrict__ dst,
                                 const float* __restrict__ g, const float* __restrict__ b,
                                 const int t)
{
  const int lane = t & 63;
  const int n    = (t >> 6) * 4 + (lane >> 4);
  const int c0   = (lane & 15) * 8;
  f32x4 va = *(const f32x4*)&src[n * 128 + c0];
  f32x4 vb = *(const f32x4*)&src[n * 128 + c0 + 4];
  float s = va.x + va.y + va.z + va.w + vb.x + vb.y + vb.z + vb.w;
  float q = va.x * va.x + va.y * va.y + va.z * va.z + va.w * va.w
          + vb.x * vb.x + vb.y * vb.y + vb.z * vb.z + vb.w * vb.w;
  #pragma unroll
  for (int m = 1; m < 16; m <<= 1) {
    s += __shfl_xor(s, m, 64);
    q += __shfl_xor(q, m, 64);
  }
  const float mean = s * 0.0078125f;
  const float var  = q * 0.0078125f - mean * mean;
  const float r    = rsqrtf(var + 1e-5f);
  f32x4 oa, ob;
  oa.x = (va.x - mean) * r * g[c0 + 0] + b[c0 + 0];
  oa.y = (va.y - mean) * r * g[c0 + 1] + b[c0 + 1];
  oa.z = (va.z - mean) * r * g[c0 + 2] + b[c0 + 2];
  oa.w = (va.w - mean) * r * g[c0 + 3] + b[c0 + 3];
  ob.x = (vb.x - mean) * r * g[c0 + 4] + b[c0 + 4];
  ob.y = (vb.y - mean) * r * g[c0 + 5] + b[c0 + 5];
  ob.z = (vb.z - mean) * r * g[c0 + 6] + b[c0 + 6];
  ob.w = (vb.w - mean) * r * g[c0 + 7] + b[c0 + 7];
  *(f32x4*)&dst[n * 128 + c0]     = oa;
  *(f32x4*)&dst[n * 128 + c0 + 4] = ob;
}

// ---------------------------------------------------------------------------
// Fused node update: attn combine -> MLP(128->128->128) -> LN1 ->
//                    MLP(128->512->128) -> LN2  (16 nodes per block)
// ---------------------------------------------------------------------------
__global__ __launch_bounds__(256)
void node_mlp(const float* __restrict__ num0, const float* __restrict__ den0,
              const float* __restrict__ num1, const float* __restrict__ den1,
              const float* __restrict__ prot,
              const float* __restrict__ Wh1, const float* __restrict__ bh1,
              const float* __restrict__ Wh2, const float* __restrict__ bh2,
              const float* __restrict__ ln1g, const float* __restrict__ ln1b,
              const float* __restrict__ Wm1, const float* __restrict__ bm1,
              const float* __restrict__ Wm2, const float* __restrict__ bm2,
              const float* __restrict__ ln2g, const float* __restrict__ ln2b,
              float* __restrict__ out)
{
  __shared__ float xs[16 * 128];   // x after LN1
  __shared__ float sc[16 * 512];   // xa | t1 (phases 1-3), t3 / pre-LN2 (phases 4-5)
  const int t    = threadIdx.x;
  const int m0   = blockIdx.x * 16;
  const int c    = t & 127;
  const int half = t >> 7;

  // phase 1: attn = num0/den0 + num1/den1  -> sc[0..2048)
  for (int idx = t; idx < 2048; idx += 256) {
    const int n = idx >> 7, cc = idx & 127;
    const int g = m0 + n, hd = cc >> 5;
    const float a0v = num0[(size_t)g * 128 + cc] / (den0[g * 4 + hd] + 1e-9f);
    const float a1v = num1[(size_t)g * 128 + cc] / (den1[g * 4 + hd] + 1e-9f);
    sc[idx] = a0v + a1v;
  }
  __syncthreads();

  // phase 2: t1 = gelu(xa @ Wh1 + bh1) -> sc[2048..4096)
  {
    float a[8] = {0, 0, 0, 0, 0, 0, 0, 0};
    for (int k = 0; k < 128; k += 4) {
      const float w0 = Wh1[(k + 0) * 128 + c];
      const float w1 = Wh1[(k + 1) * 128 + c];
      const float w2 = Wh1[(k + 2) * 128 + c];
      const float w3 = Wh1[(k + 3) * 128 + c];
      #pragma unroll
      for (int i = 0; i < 8; ++i) {
        const f32x4 xv = *(const f32x4*)&sc[(half * 8 + i) * 128 + k];
        a[i] = fmaf(xv.w, w3, fmaf(xv.z, w2, fmaf(xv.y, w1, fmaf(xv.x, w0, a[i]))));
      }
    }
    const float bb = bh1[c];
    #pragma unroll
    for (int i = 0; i < 8; ++i)
      sc[2048 + (half * 8 + i) * 128 + c] = gelu_tanh(a[i] + bb);
  }
  __syncthreads();

  // phase 3: x = prot + t1 @ Wh2 + bh2 -> xs, then LN1 in place
  {
    float a[8] = {0, 0, 0, 0, 0, 0, 0, 0};
    for (int k = 0; k < 128; k += 4) {
      const float w0 = Wh2[(k + 0) * 128 + c];
      const float w1 = Wh2[(k + 1) * 128 + c];
      const float w2 = Wh2[(k + 2) * 128 + c];
      const float w3 = Wh2[(k + 3) * 128 + c];
      #pragma unroll
      for (int i = 0; i < 8; ++i) {
        const f32x4 xv = *(const f32x4*)&sc[2048 + (half * 8 + i) * 128 + k];
        a[i] = fmaf(xv.w, w3, fmaf(xv.z, w2, fmaf(xv.y, w1, fmaf(xv.x, w0, a[i]))));
      }
    }
    const float bb = bh2[c];
    #pragma unroll
    for (int i = 0; i < 8; ++i) {
      const int n = half * 8 + i;
      xs[n * 128 + c] = a[i] + bb + prot[(size_t)(m0 + n) * 128 + c];
    }
  }
  __syncthreads();
  ln_rows16(xs, xs, ln1g, ln1b, t);
  __syncthreads();

  // phase 4: t3 = gelu(x @ Wm1 + bm1) -> sc[0..8192)
  {
    float a0[16], a1[16];
    #pragma unroll
    for (int i = 0; i < 16; ++i) { a0[i] = 0.f; a1[i] = 0.f; }
    for (int k = 0; k < 128; k += 4) {
      const float u0 = Wm1[(size_t)(k + 0) * 512 + t];
      const float u1 = Wm1[(size_t)(k + 1) * 512 + t];
      const float u2 = Wm1[(size_t)(k + 2) * 512 + t];
      const float u3 = Wm1[(size_t)(k + 3) * 512 + t];
      const float v0 = Wm1[(size_t)(k + 0) * 512 + t + 256];
      const float v1 = Wm1[(size_t)(k + 1) * 512 + t + 256];
      const float v2 = Wm1[(size_t)(k + 2) * 512 + t + 256];
      const float v3 = Wm1[(size_t)(k + 3) * 512 + t + 256];
      #pragma unroll
      for (int i = 0; i < 16; ++i) {
        const f32x4 xv = *(const f32x4*)&xs[i * 128 + k];
        a0[i] = fmaf(xv.w, u3, fmaf(xv.z, u2, fmaf(xv.y, u1, fmaf(xv.x, u0, a0[i]))));
        a1[i] = fmaf(xv.w, v3, fmaf(xv.z, v2, fmaf(xv.y, v1, fmaf(xv.x, v0, a1[i]))));
      }
    }
    const float bb0 = bm1[t], bb1 = bm1[t + 256];
    #pragma unroll
    for (int i = 0; i < 16; ++i) {
      sc[i * 512 + t]       = gelu_tanh(a0[i] + bb0);
      sc[i * 512 + t + 256] = gelu_tanh(a1[i] + bb1);
    }
  }
  __syncthreads();

  // phase 5: pre = x + t3 @ Wm2 + bm2 -> sc[0..2048), then LN2 -> out
  {
    float a[8] = {0, 0, 0, 0, 0, 0, 0, 0};
    for (int k = 0; k < 512; k += 4) {
      const float w0 = Wm2[(size_t)(k + 0) * 128 + c];
      const float w1 = Wm2[(size_t)(k + 1) * 128 + c];
      const float w2 = Wm2[(size_t)(k + 2) * 128 + c];
      const float w3 = Wm2[(size_t)(k + 3) * 128 + c];
      #pragma unroll
      for (int i = 0; i < 8; ++i) {
        const f32x4 tv = *(const f32x4*)&sc[(half * 8 + i) * 512 + k];
        a[i] = fmaf(tv.w, w3, fmaf(tv.z, w2, fmaf(tv.y, w1, fmaf(tv.x, w0, a[i]))));
      }
    }
    __syncthreads();   // all t3 reads complete before overwrite
    const float bb = bm2[c];
    #pragma unroll
    for (int i = 0; i < 8; ++i) {
      const int n = half * 8 + i;
      sc[n * 128 + c] = a[i] + bb + xs[n * 128 + c];
    }
  }
  __syncthreads();
  ln_rows16(sc, out + (size_t)m0 * 128, ln2g, ln2b, t);
}

// ---------------------------------------------------------------------------
extern "C" void kernel_launch(void* const* d_in, const int* in_sizes, int n_in,
                              void* d_out, int out_size, void* d_ws, size_t ws_size,
                              hipStream_t stream)
{
  const float* src_exp = (const float*)d_in[0];
  const float* prot    = (const float*)d_in[1];
  const float* pvec    = (const float*)d_in[2];
  const int*   eidx0   = (const int*)d_in[3];
  const float* lig     = (const float*)d_in[4];
  const float* eattr   = (const float*)d_in[5];
  const int*   eidx1   = (const int*)d_in[6];
  const float* Watt0 = (const float*)d_in[7];
  const float* batt0 = (const float*)d_in[8];
  const float* a0    = (const float*)d_in[9];
  const float* Wval0 = (const float*)d_in[10];
  const float* bval0 = (const float*)d_in[11];
  const float* Watt1 = (const float*)d_in[12];
  const float* batt1 = (const float*)d_in[13];
  const float* a1    = (const float*)d_in[14];
  const float* Wval1 = (const float*)d_in[15];
  const float* bval1 = (const float*)d_in[16];
  const float* Wh1  = (const float*)d_in[17];
  const float* bh1  = (const float*)d_in[18];
  const float* Wh2  = (const float*)d_in[19];
  const float* bh2  = (const float*)d_in[20];
  const float* ln1g = (const float*)d_in[21];
  const float* ln1b = (const float*)d_in[22];
  const float* Wm1  = (const float*)d_in[23];
  const float* bm1  = (const float*)d_in[24];
  const float* Wm2  = (const float*)d_in[25];
  const float* bm2  = (const float*)d_in[26];
  const float* ln2g = (const float*)d_in[27];
  const float* ln2b = (const float*)d_in[28];

  float* num0 = (float*)d_ws;
  float* num1 = num0 + (size_t)N_PROT * 128;
  float* den0 = num1 + (size_t)N_PROT * 128;
  float* den1 = den0 + (size_t)N_PROT * 4;
  ushort_t* Bt0 = (ushort_t*)(den1 + (size_t)N_PROT * 4);
  ushort_t* Bt1 = Bt0 + 576 * 256;

  // zero accumulators (num0, num1, den0, den1 are contiguous)
  hipMemsetAsync(d_ws, 0, ((size_t)N_PROT * 128 * 2 + (size_t)N_PROT * 8) * sizeof(float), stream);

  build_bt<<<(576 * 256) / 256, 256, 0, stream>>>(Watt0, Wval0, Bt0, 576);
  build_bt<<<(384 * 256) / 256, 256, 0, stream>>>(Watt1, Wval1, Bt1, 384);

  edge_gat<0><<<E_PP / 64, 256, 0, stream>>>(src_exp, prot, nullptr, eidx0, Bt0,
                                             batt0, a0, bval0, num0, den0);
  edge_gat<1><<<E_LP / 64, 256, 0, stream>>>(lig, prot, eattr, eidx1, Bt1,
                                             batt1, a1, bval1, num1, den1);

  node_mlp<<<N_PROT / 16, 256, 0, stream>>>(num0, den0, num1, den1, prot,
                                            Wh1, bh1, Wh2, bh2, ln1g, ln1b,
                                            Wm1, bm1, Wm2, bm2, ln2g, ln2b,
                                            (float*)d_out);

  // prot_vectors pass-through
  hipMemcpyAsync((float*)d_out + (size_t)N_PROT * 128, pvec,
                 (size_t)N_PROT * 12 * sizeof(float), hipMemcpyDeviceToDevice, stream);
}

// Round 3
// 368.910 us; speedup vs baseline: 1.1036x; 1.1036x over previous
//
#include <hip/hip_runtime.h>

#define N_PROT 8192
#define E_PP   163840
#define E_LP   81920
#define NBLK0  (E_PP / 64)   // 2560
#define NBLK1  (E_LP / 64)   // 1280

typedef float        f32x4 __attribute__((ext_vector_type(4)));
typedef unsigned int u32x4 __attribute__((ext_vector_type(4)));
typedef short        s16x8 __attribute__((ext_vector_type(8)));
typedef unsigned short ushort_t;
typedef __attribute__((address_space(1))) const void* gas_t;
typedef __attribute__((address_space(3))) void*       las_t;

union frag_cast { u32x4 u; s16x8 s; };

__device__ inline unsigned short f2bf(float f) {
  unsigned int u = __float_as_uint(f);
  u = u + 0x7FFFu + ((u >> 16) & 1u);   // RTNE
  return (unsigned short)(u >> 16);
}

__device__ inline float gelu_tanh(float x) {
  const float c0 = 0.7978845608028654f;
  float inner = c0 * (x + 0.044715f * x * x * x);
  return 0.5f * x * (1.0f + tanhf(inner));
}

__device__ inline void gload16(const void* g, void* l) {
  __builtin_amdgcn_global_load_lds((gas_t)g, (las_t)l, 16, 0, 0);
}

// ---------------------------------------------------------------------------
// Pre-transpose weights [K][128]+[K][128] -> k-inner bf16 [K/8][256][8]
// ---------------------------------------------------------------------------
__global__ void build_bt(const float* __restrict__ Watt, const float* __restrict__ Wval,
                         ushort_t* __restrict__ Bt, int K)
{
  int i = blockIdx.x * 256 + threadIdx.x;
  if (i >= K * 256) return;
  int k = i >> 8, n = i & 255;
  float v = (n < 128) ? Watt[(size_t)k * 128 + n] : Wval[(size_t)k * 128 + (n - 128)];
  Bt[(size_t)(k >> 3) * 2048 + n * 8 + (k & 7)] = f2bf(v);
}

// ---------------------------------------------------------------------------
// Edge GATv2 body: gathered GEMM [64 x K] @ [K x 256], 2-phase pipelined
// (double-buffered LDS, global_load_lds for B, counted vmcnt, 1 barrier/step)
// MODE 0: pp (z = [src_exp(448) | prot[sink](128)]), K=576
// MODE 1: lp (z = [lig[src](128) | prot[sink](128) | eattr(128)]), K=384
// ---------------------------------------------------------------------------
template<int MODE>
__device__ __forceinline__ void edge_body(
    int bid, ushort_t* AsmP, ushort_t* BsmP, float* esm, int* ssink,
    const float* __restrict__ Afeat, const float* __restrict__ prot,
    const float* __restrict__ eattr, const int* __restrict__ eidx,
    const ushort_t* __restrict__ Bt,
    const float* __restrict__ batt, const float* __restrict__ avec,
    const float* __restrict__ bval,
    float* __restrict__ num, float* __restrict__ den)
{
  constexpr int K  = (MODE == 0) ? 576 : 384;
  constexpr int E  = (MODE == 0) ? E_PP : E_LP;
  constexpr int NT = K / 32;

  const int t    = threadIdx.x;
  const int lane = t & 63;
  const int w    = t >> 6;
  const int m0   = bid * 64;

  const int lr  = t >> 2;        // row this thread stages
  const int lc  = t & 3;         // 8-float chunk within the 32-wide k-step
  const int eid = m0 + lr;
  const int snk = eidx[E + eid];
  int src = 0;
  if (MODE == 1) src = eidx[eid];
  if (lc == 0) ssink[lr] = snk;

  // A source base pointers (per-thread row + chunk)
  const float* apM;
  const float* apP;
  const float* apE = nullptr;
  if (MODE == 0) {
    apM = Afeat + (size_t)eid * 448 + lc * 8;
    apP = prot  + (size_t)snk * 128 + lc * 8;
  } else {
    apM = Afeat + (size_t)src * 128 + lc * 8;
    apP = prot  + (size_t)snk * 128 + lc * 8;
    apE = eattr + (size_t)eid * 128 + lc * 8;
  }
  auto aptr = [&](int k0) -> const float* {
    if (MODE == 0) return (k0 < 448) ? (apM + k0) : (apP + (k0 - 448));
    const int r = k0 >> 7, kk = k0 & 127;
    return (r == 0) ? (apM + kk) : (r == 1) ? (apP + kk) : (apE + kk);
  };

  const u32x4* btv = (const u32x4*)Bt;
  // B stage: 4 x global_load_lds (16B/lane) per wave; LDS dest wave-uniform
  auto stageB = [&](int k0, int b) {
    const u32x4* gp = btv + (size_t)k0 * 32 + w * 64 + lane;
    char* lb = (char*)BsmP + b * 16384 + w * 1024;
    #pragma unroll
    for (int q = 0; q < 4; ++q)
      gload16(gp + q * 256, lb + q * 4096);
  };
  // A write: cvt 8 f32 -> bf16, 16B store to swizzled LDS slot
  const int a_off = lr * 64 + ((lc ^ ((lr >> 1) & 3)) * 16);
  auto writeA = [&](const f32x4& f0, const f32x4& f1, int b) {
    union { unsigned short u[8]; u32x4 v; } pk;
    pk.u[0] = f2bf(f0.x); pk.u[1] = f2bf(f0.y); pk.u[2] = f2bf(f0.z); pk.u[3] = f2bf(f0.w);
    pk.u[4] = f2bf(f1.x); pk.u[5] = f2bf(f1.y); pk.u[6] = f2bf(f1.z); pk.u[7] = f2bf(f1.w);
    *(u32x4*)((char*)AsmP + b * 4096 + a_off) = pk.v;
  };

  f32x4 acc[4][4];
  #pragma unroll
  for (int i = 0; i < 4; ++i)
    #pragma unroll
    for (int j = 0; j < 4; ++j)
      acc[i][j] = (f32x4){0.f, 0.f, 0.f, 0.f};

  const int l15 = lane & 15;
  const int kb  = lane >> 4;

  // ---- prologue: A(0)->ga, B(0)->buf0, A(1)->gb, A(0)->LDS, wait, barrier
  f32x4 ga0, ga1, gb0, gb1;
  { const float* p0 = aptr(0);  ga0 = *(const f32x4*)p0; ga1 = *(const f32x4*)(p0 + 4); }
  __builtin_amdgcn_sched_barrier(0);
  stageB(0, 0);
  __builtin_amdgcn_sched_barrier(0);
  { const float* p1 = aptr(32); gb0 = *(const f32x4*)p1; gb1 = *(const f32x4*)(p1 + 4); }
  __builtin_amdgcn_sched_barrier(0);
  writeA(ga0, ga1, 0);
  asm volatile("s_waitcnt vmcnt(2) lgkmcnt(0)\n\ts_barrier" ::: "memory");

  // ---- main loop: per step s consume buf p, prefetch B(s+1), A(s+2)
  #pragma unroll
  for (int s = 0; s < NT; ++s) {
    const int p = s & 1;
    if (s + 1 < NT) {
      stageB((s + 1) * 32, p ^ 1);
      __builtin_amdgcn_sched_barrier(0);
    }
    if (s + 2 < NT) {
      const float* pn = aptr((s + 2) * 32);
      f32x4 n0 = *(const f32x4*)pn, n1 = *(const f32x4*)(pn + 4);
      if (s & 1) { gb0 = n0; gb1 = n1; } else { ga0 = n0; ga1 = n1; }
    }
    __builtin_amdgcn_sched_barrier(0);

    frag_cast af[4], bfr[4];
    #pragma unroll
    for (int mb = 0; mb < 4; ++mb) {
      const int row = mb * 16 + l15;
      af[mb].u = *(const u32x4*)((const char*)AsmP + p * 4096 + row * 64
                                 + ((kb ^ ((row >> 1) & 3)) * 16));
    }
    #pragma unroll
    for (int nb = 0; nb < 4; ++nb) {
      const int n = w * 64 + nb * 16 + l15;
      bfr[nb].u = *(const u32x4*)((const char*)BsmP + p * 16384 + kb * 4096 + n * 16);
    }
    #pragma unroll
    for (int mb = 0; mb < 4; ++mb)
      #pragma unroll
      for (int nb = 0; nb < 4; ++nb)
        acc[mb][nb] = __builtin_amdgcn_mfma_f32_16x16x32_bf16(
            af[mb].s, bfr[nb].s, acc[mb][nb], 0, 0, 0);
    __builtin_amdgcn_sched_barrier(0);

    if (s + 1 < NT) {
      if (s & 1) writeA(ga0, ga1, p ^ 1);   // A(s+1) lives in the other reg set
      else       writeA(gb0, gb1, p ^ 1);
      if (s + 2 < NT)
        asm volatile("s_waitcnt vmcnt(2) lgkmcnt(0)\n\ts_barrier" ::: "memory");
      else
        asm volatile("s_waitcnt vmcnt(0) lgkmcnt(0)\n\ts_barrier" ::: "memory");
    }
  }

  // ---- attention logits (waves 0,1 own cols 0..127 = Watt output) ----
  if (w < 2) {
    #pragma unroll
    for (int hl = 0; hl < 2; ++hl) {
      const int   head = w * 2 + hl;
      const float a_lo = avec[head * 32 + l15];
      const float a_hi = avec[head * 32 + 16 + l15];
      const float b_lo = batt[head * 32 + l15];
      const float b_hi = batt[head * 32 + 16 + l15];
      #pragma unroll
      for (int mb = 0; mb < 4; ++mb) {
        #pragma unroll
        for (int j = 0; j < 4; ++j) {
          float hlo = acc[mb][2 * hl][j]     + b_lo;
          float hhi = acc[mb][2 * hl + 1][j] + b_hi;
          hlo = (hlo > 0.f) ? hlo : 0.2f * hlo;
          hhi = (hhi > 0.f) ? hhi : 0.2f * hhi;
          float pv = hlo * a_lo + hhi * a_hi;
          pv += __shfl_xor(pv, 1, 64);
          pv += __shfl_xor(pv, 2, 64);
          pv += __shfl_xor(pv, 4, 64);
          pv += __shfl_xor(pv, 8, 64);
          if (l15 == 0) {
            const float ev  = __expf(pv);   // no max-sub: logits bounded (~|4|)
            const int   row = mb * 16 + kb * 4 + j;
            esm[row * 4 + head] = ev;
            atomicAdd(&den[(size_t)ssink[row] * 4 + head], ev);
          }
        }
      }
    }
  }
  __syncthreads();
  // ---- value accumulation (waves 2,3 own cols 128..255 = Wval output) ----
  if (w >= 2) {
    #pragma unroll
    for (int nb = 0; nb < 4; ++nb) {
      const int   col = (w - 2) * 64 + nb * 16 + l15;
      const float bv  = bval[col];
      const int   hd  = col >> 5;
      #pragma unroll
      for (int mb = 0; mb < 4; ++mb) {
        #pragma unroll
        for (int j = 0; j < 4; ++j) {
          const int   row = mb * 16 + kb * 4 + j;
          const float v   = acc[mb][nb][j] + bv;
          atomicAdd(&num[(size_t)ssink[row] * 128 + col], v * esm[row * 4 + hd]);
        }
      }
    }
  }
}

// ---------------------------------------------------------------------------
// Fused edge kernel: blocks [0, NBLK0) do pp edges, [NBLK0, NBLK0+NBLK1) lp
// ---------------------------------------------------------------------------
__global__ __launch_bounds__(256, 3)
void edge_gat_fused(const float* __restrict__ src_exp, const float* __restrict__ prot,
                    const float* __restrict__ lig, const float* __restrict__ eattr,
                    const int* __restrict__ eidx0, const int* __restrict__ eidx1,
                    const ushort_t* __restrict__ Bt0, const ushort_t* __restrict__ Bt1,
                    const float* __restrict__ batt0, const float* __restrict__ a0,
                    const float* __restrict__ bval0,
                    const float* __restrict__ batt1, const float* __restrict__ a1,
                    const float* __restrict__ bval1,
                    float* __restrict__ num0, float* __restrict__ den0,
                    float* __restrict__ num1, float* __restrict__ den1)
{
  __shared__ alignas(16) ushort_t AsmS[2 * 2048];   //  8 KB (double-buffered A)
  __shared__ alignas(16) ushort_t BsmS[2 * 8192];   // 32 KB (double-buffered B)
  __shared__ float esm[64 * 4];
  __shared__ int   ssink[64];

  const int b = blockIdx.x;
  if (b < NBLK0)
    edge_body<0>(b, AsmS, BsmS, esm, ssink, src_exp, prot, nullptr, eidx0,
                 Bt0, batt0, a0, bval0, num0, den0);
  else
    edge_body<1>(b - NBLK0, AsmS, BsmS, esm, ssink, lig, prot, eattr, eidx1,
                 Bt1, batt1, a1, bval1, num1, den1);
}

// ---------------------------------------------------------------------------
// LN over 16 rows of 128 (4 waves; wave handles 4 rows, 16 lanes x 8 cols)
// ---------------------------------------------------------------------------
__device__ inline void ln_rows16(const float* __restrict__ src, float* __restrict__ dst,
                                 const float* __restrict__ g, const float* __restrict__ b,
                                 const int t)
{
  const int lane = t & 63;
  const int n    = (t >> 6) * 4 + (lane >> 4);
  const int c0   = (lane & 15) * 8;
  f32x4 va = *(const f32x4*)&src[n * 128 + c0];
  f32x4 vb = *(const f32x4*)&src[n * 128 + c0 + 4];
  float s = va.x + va.y + va.z + va.w + vb.x + vb.y + vb.z + vb.w;
  float q = va.x * va.x + va.y * va.y + va.z * va.z + va.w * va.w
          + vb.x * vb.x + vb.y * vb.y + vb.z * vb.z + vb.w * vb.w;
  #pragma unroll
  for (int m = 1; m < 16; m <<= 1) {
    s += __shfl_xor(s, m, 64);
    q += __shfl_xor(q, m, 64);
  }
  const float mean = s * 0.0078125f;
  const float var  = q * 0.0078125f - mean * mean;
  const float r    = rsqrtf(var + 1e-5f);
  f32x4 oa, ob;
  oa.x = (va.x - mean) * r * g[c0 + 0] + b[c0 + 0];
  oa.y = (va.y - mean) * r * g[c0 + 1] + b[c0 + 1];
  oa.z = (va.z - mean) * r * g[c0 + 2] + b[c0 + 2];
  oa.w = (va.w - mean) * r * g[c0 + 3] + b[c0 + 3];
  ob.x = (vb.x - mean) * r * g[c0 + 4] + b[c0 + 4];
  ob.y = (vb.y - mean) * r * g[c0 + 5] + b[c0 + 5];
  ob.z = (vb.z - mean) * r * g[c0 + 6] + b[c0 + 6];
  ob.w = (vb.w - mean) * r * g[c0 + 7] + b[c0 + 7];
  *(f32x4*)&dst[n * 128 + c0]     = oa;
  *(f32x4*)&dst[n * 128 + c0 + 4] = ob;
}

// ---------------------------------------------------------------------------
// Fused node update: attn combine -> MLP(128->128->128) -> LN1 ->
//                    MLP(128->512->128) -> LN2  (16 nodes per block)
// ---------------------------------------------------------------------------
__global__ __launch_bounds__(256)
void node_mlp(const float* __restrict__ num0, const float* __restrict__ den0,
              const float* __restrict__ num1, const float* __restrict__ den1,
              const float* __restrict__ prot,
              const float* __restrict__ Wh1, const float* __restrict__ bh1,
              const float* __restrict__ Wh2, const float* __restrict__ bh2,
              const float* __restrict__ ln1g, const float* __restrict__ ln1b,
              const float* __restrict__ Wm1, const float* __restrict__ bm1,
              const float* __restrict__ Wm2, const float* __restrict__ bm2,
              const float* __restrict__ ln2g, const float* __restrict__ ln2b,
              float* __restrict__ out)
{
  __shared__ float xs[16 * 128];
  __shared__ float sc[16 * 512];
  const int t    = threadIdx.x;
  const int m0   = blockIdx.x * 16;
  const int c    = t & 127;
  const int half = t >> 7;

  for (int idx = t; idx < 2048; idx += 256) {
    const int n = idx >> 7, cc = idx & 127;
    const int g = m0 + n, hd = cc >> 5;
    const float a0v = num0[(size_t)g * 128 + cc] / (den0[g * 4 + hd] + 1e-9f);
    const float a1v = num1[(size_t)g * 128 + cc] / (den1[g * 4 + hd] + 1e-9f);
    sc[idx] = a0v + a1v;
  }
  __syncthreads();

  {
    float a[8] = {0, 0, 0, 0, 0, 0, 0, 0};
    for (int k = 0; k < 128; k += 4) {
      const float w0 = Wh1[(k + 0) * 128 + c];
      const float w1 = Wh1[(k + 1) * 128 + c];
      const float w2 = Wh1[(k + 2) * 128 + c];
      const float w3 = Wh1[(k + 3) * 128 + c];
      #pragma unroll
      for (int i = 0; i < 8; ++i) {
        const f32x4 xv = *(const f32x4*)&sc[(half * 8 + i) * 128 + k];
        a[i] = fmaf(xv.w, w3, fmaf(xv.z, w2, fmaf(xv.y, w1, fmaf(xv.x, w0, a[i]))));
      }
    }
    const float bb = bh1[c];
    #pragma unroll
    for (int i = 0; i < 8; ++i)
      sc[2048 + (half * 8 + i) * 128 + c] = gelu_tanh(a[i] + bb);
  }
  __syncthreads();

  {
    float a[8] = {0, 0, 0, 0, 0, 0, 0, 0};
    for (int k = 0; k < 128; k += 4) {
      const float w0 = Wh2[(k + 0) * 128 + c];
      const float w1 = Wh2[(k + 1) * 128 + c];
      const float w2 = Wh2[(k + 2) * 128 + c];
      const float w3 = Wh2[(k + 3) * 128 + c];
      #pragma unroll
      for (int i = 0; i < 8; ++i) {
        const f32x4 xv = *(const f32x4*)&sc[2048 + (half * 8 + i) * 128 + k];
        a[i] = fmaf(xv.w, w3, fmaf(xv.z, w2, fmaf(xv.y, w1, fmaf(xv.x, w0, a[i]))));
      }
    }
    const float bb = bh2[c];
    #pragma unroll
    for (int i = 0; i < 8; ++i) {
      const int n = half * 8 + i;
      xs[n * 128 + c] = a[i] + bb + prot[(size_t)(m0 + n) * 128 + c];
    }
  }
  __syncthreads();
  ln_rows16(xs, xs, ln1g, ln1b, t);
  __syncthreads();

  {
    float a0[16], a1[16];
    #pragma unroll
    for (int i = 0; i < 16; ++i) { a0[i] = 0.f; a1[i] = 0.f; }
    for (int k = 0; k < 128; k += 4) {
      const float u0 = Wm1[(size_t)(k + 0) * 512 + t];
      const float u1 = Wm1[(size_t)(k + 1) * 512 + t];
      const float u2 = Wm1[(size_t)(k + 2) * 512 + t];
      const float u3 = Wm1[(size_t)(k + 3) * 512 + t];
      const float v0 = Wm1[(size_t)(k + 0) * 512 + t + 256];
      const float v1 = Wm1[(size_t)(k + 1) * 512 + t + 256];
      const float v2 = Wm1[(size_t)(k + 2) * 512 + t + 256];
      const float v3 = Wm1[(size_t)(k + 3) * 512 + t + 256];
      #pragma unroll
      for (int i = 0; i < 16; ++i) {
        const f32x4 xv = *(const f32x4*)&xs[i * 128 + k];
        a0[i] = fmaf(xv.w, u3, fmaf(xv.z, u2, fmaf(xv.y, u1, fmaf(xv.x, u0, a0[i]))));
        a1[i] = fmaf(xv.w, v3, fmaf(xv.z, v2, fmaf(xv.y, v1, fmaf(xv.x, v0, a1[i]))));
      }
    }
    const float bb0 = bm1[t], bb1 = bm1[t + 256];
    #pragma unroll
    for (int i = 0; i < 16; ++i) {
      sc[i * 512 + t]       = gelu_tanh(a0[i] + bb0);
      sc[i * 512 + t + 256] = gelu_tanh(a1[i] + bb1);
    }
  }
  __syncthreads();

  {
    float a[8] = {0, 0, 0, 0, 0, 0, 0, 0};
    for (int k = 0; k < 512; k += 4) {
      const float w0 = Wm2[(size_t)(k + 0) * 128 + c];
      const float w1 = Wm2[(size_t)(k + 1) * 128 + c];
      const float w2 = Wm2[(size_t)(k + 2) * 128 + c];
      const float w3 = Wm2[(size_t)(k + 3) * 128 + c];
      #pragma unroll
      for (int i = 0; i < 8; ++i) {
        const f32x4 tv = *(const f32x4*)&sc[(half * 8 + i) * 512 + k];
        a[i] = fmaf(tv.w, w3, fmaf(tv.z, w2, fmaf(tv.y, w1, fmaf(tv.x, w0, a[i]))));
      }
    }
    __syncthreads();
    const float bb = bm2[c];
    #pragma unroll
    for (int i = 0; i < 8; ++i) {
      const int n = half * 8 + i;
      sc[n * 128 + c] = a[i] + bb + xs[n * 128 + c];
    }
  }
  __syncthreads();
  ln_rows16(sc, out + (size_t)m0 * 128, ln2g, ln2b, t);
}

// ---------------------------------------------------------------------------
extern "C" void kernel_launch(void* const* d_in, const int* in_sizes, int n_in,
                              void* d_out, int out_size, void* d_ws, size_t ws_size,
                              hipStream_t stream)
{
  const float* src_exp = (const float*)d_in[0];
  const float* prot    = (const float*)d_in[1];
  const float* pvec    = (const float*)d_in[2];
  const int*   eidx0   = (const int*)d_in[3];
  const float* lig     = (const float*)d_in[4];
  const float* eattr   = (const float*)d_in[5];
  const int*   eidx1   = (const int*)d_in[6];
  const float* Watt0 = (const float*)d_in[7];
  const float* batt0 = (const float*)d_in[8];
  const float* a0    = (const float*)d_in[9];
  const float* Wval0 = (const float*)d_in[10];
  const float* bval0 = (const float*)d_in[11];
  const float* Watt1 = (const float*)d_in[12];
  const float* batt1 = (const float*)d_in[13];
  const float* a1    = (const float*)d_in[14];
  const float* Wval1 = (const float*)d_in[15];
  const float* bval1 = (const float*)d_in[16];
  const float* Wh1  = (const float*)d_in[17];
  const float* bh1  = (const float*)d_in[18];
  const float* Wh2  = (const float*)d_in[19];
  const float* bh2  = (const float*)d_in[20];
  const float* ln1g = (const float*)d_in[21];
  const float* ln1b = (const float*)d_in[22];
  const float* Wm1  = (const float*)d_in[23];
  const float* bm1  = (const float*)d_in[24];
  const float* Wm2  = (const float*)d_in[25];
  const float* bm2  = (const float*)d_in[26];
  const float* ln2g = (const float*)d_in[27];
  const float* ln2b = (const float*)d_in[28];

  float* num0 = (float*)d_ws;
  float* num1 = num0 + (size_t)N_PROT * 128;
  float* den0 = num1 + (size_t)N_PROT * 128;
  float* den1 = den0 + (size_t)N_PROT * 4;
  ushort_t* Bt0 = (ushort_t*)(den1 + (size_t)N_PROT * 4);
  ushort_t* Bt1 = Bt0 + 576 * 256;

  hipMemsetAsync(d_ws, 0, ((size_t)N_PROT * 128 * 2 + (size_t)N_PROT * 8) * sizeof(float), stream);

  build_bt<<<(576 * 256) / 256, 256, 0, stream>>>(Watt0, Wval0, Bt0, 576);
  build_bt<<<(384 * 256) / 256, 256, 0, stream>>>(Watt1, Wval1, Bt1, 384);

  edge_gat_fused<<<NBLK0 + NBLK1, 256, 0, stream>>>(
      src_exp, prot, lig, eattr, eidx0, eidx1, Bt0, Bt1,
      batt0, a0, bval0, batt1, a1, bval1, num0, den0, num1, den1);

  node_mlp<<<N_PROT / 16, 256, 0, stream>>>(num0, den0, num1, den1, prot,
                                            Wh1, bh1, Wh2, bh2, ln1g, ln1b,
                                            Wm1, bm1, Wm2, bm2, ln2g, ln2b,
                                            (float*)d_out);

  hipMemcpyAsync((float*)d_out + (size_t)N_PROT * 128, pvec,
                 (size_t)N_PROT * 12 * sizeof(float), hipMemcpyDeviceToDevice, stream);
}